// Round 3
// baseline (136.617 us; speedup 1.0000x reference)
//
#include <hip/hip_runtime.h>

// Problem constants (from reference setup_inputs)
#define BATCH 256
#define SEQ   2048
#define VOCAB 128000
#define HALF   64000            // floats of w_a owned per block
#define PCHUNK 16000            // dedup-table slots per phase (62.5 KB LDS)
#define NPH    4                // phases per block: 4 * 16000 = 64000

typedef float v4f __attribute__((ext_vector_type(4)));
typedef int   v4i __attribute__((ext_vector_type(4)));
typedef float v2f __attribute__((ext_vector_type(2)));
typedef int   v2i __attribute__((ext_vector_type(2)));

// lgkmcnt-only barrier: orders LDS (init -> atomics -> pass2 -> stream-read ->
// re-init) WITHOUT draining vmcnt. Global stores from previous phases stay in
// flight across the barrier, so the w_a write stream pipelines through all
// phases instead of stalling on a full vmcnt(0) drain at every __syncthreads.
#define LBAR() do { asm volatile("s_waitcnt lgkmcnt(0)" ::: "memory"); \
                    __builtin_amdgcn_s_barrier(); } while (0)

// Grid = 512 blocks of 1024 threads. Block (r, h) computes row r's softmax
// once (vs 8x in the previous 2048-block version), then runs 4 sequential
// dedup phases over its 64000-slot half of the vocab, streaming each 16000
// -slot chunk to global as soon as its table is resolved.
//
// Dedup (last-write-wins):
//   LDS table as int, init -1.
//   atomicMax(table[tok-base], position_idx) for in-range tokens
//   winner (table[v]==idx) overwrites with f32 weight bits (sign bit 0)
//   stream: bits<0 => empty => 0.0f
// Every w_a byte goes to HBM exactly once, coalesced float4.
__global__ __launch_bounds__(1024, 4)
void softmax_scatter_phased(const float* __restrict__ w_es,
                            const int*   __restrict__ x,
                            float* __restrict__ w_a,     // [BATCH, VOCAB]
                            float* __restrict__ w_out)   // [BATCH, SEQ]
{
    __shared__ int   chunk[PCHUNK];   // 62.5 KB -> 2 blocks/CU (125 KB of 160)
    __shared__ float red[32];         // [0..15] max partials, [16..31] sums

    const int bid = blockIdx.x;
    // XCD swizzle: both half-blocks of row r have bid % 8 == r % 8 -> same
    // XCD L2 -> row's w_es/x fetched from HBM once.
    const int r = bid & (BATCH - 1);
    const int h = bid >> 8;            // 0 or 1
    const int base0 = h * HALF;

    const int t = threadIdx.x;         // 0..1023
    const int lane = t & 63;
    const int wid  = t >> 6;           // 0..15

    // ---- init table for phase 0 (covered by softmax's syncthreads) ----
    {
        const v4i m1 = (v4i)(-1);
        #pragma unroll
        for (int j0 = 0; j0 < 4096; j0 += 1024) {
            const int j = j0 + t;
            if (j < (PCHUNK >> 2)) ((v4i*)chunk)[j] = m1;
        }
    }

    // ---- softmax over the full row: 2 scores per thread ----
    const float* rowp = w_es + (size_t)r * SEQ;
    const v2f a = ((const v2f*)rowp)[t];

    float m = fmaxf(a.x, a.y);
    #pragma unroll
    for (int off = 32; off > 0; off >>= 1)
        m = fmaxf(m, __shfl_down(m, off, 64));
    if (lane == 0) red[wid] = m;
    __syncthreads();                   // also publishes the phase-0 init
    m = red[0];
    #pragma unroll
    for (int k = 1; k < 16; ++k) m = fmaxf(m, red[k]);

    const float e0 = __expf(a.x - m);
    const float e1 = __expf(a.y - m);
    float s = e0 + e1;
    #pragma unroll
    for (int off = 32; off > 0; off >>= 1)
        s += __shfl_down(s, off, 64);
    if (lane == 0) red[16 + wid] = s;
    __syncthreads();
    s = red[16];
    #pragma unroll
    for (int k = 1; k < 16; ++k) s += red[16 + k];

    const float inv = 1.0f / s;
    const float w0 = e0 * inv;
    const float w1 = e1 * inv;

    // ---- h==0 blocks also write the weights output ----
    if (h == 0) {
        v2f wv; wv.x = w0; wv.y = w1;
        ((v2f*)(w_out + (size_t)r * SEQ))[t] = wv;
    }

    // ---- token ids: 2 per thread ----
    const v2i xv = ((const v2i*)(x + (size_t)r * SEQ))[t];
    const int i0 = 2 * t;
    const int i1 = 2 * t + 1;

    float* const growp = w_a + (size_t)r * VOCAB;

    // ---- 4 dedup+stream phases over this block's half of the vocab ----
    for (int p = 0; p < NPH; ++p) {
        const int pb = base0 + p * PCHUNK;
        const int v0 = xv.x - pb;
        const int v1 = xv.y - pb;
        const bool in0 = (unsigned)v0 < (unsigned)PCHUNK;
        const bool in1 = (unsigned)v1 < (unsigned)PCHUNK;

        // pass 1: max position index per hit slot
        if (in0) atomicMax(&chunk[v0], i0);
        if (in1) atomicMax(&chunk[v1], i1);
        LBAR();

        // pass 2: winner writes its weight (f32 bits, sign >= 0)
        if (in0 && chunk[v0] == i0) ((float*)chunk)[v0] = w0;
        if (in1 && chunk[v1] == i1) ((float*)chunk)[v1] = w1;
        LBAR();

        // pass 3: stream chunk to global; negative bits => empty => 0
        float* gp = growp + pb;
        #pragma unroll
        for (int j0 = 0; j0 < 4096; j0 += 1024) {
            const int j = j0 + t;
            if (j < (PCHUNK >> 2)) {
                v4i b = ((const v4i*)chunk)[j];
                v4f o;
                o.x = (b.x < 0) ? 0.0f : __int_as_float(b.x);
                o.y = (b.y < 0) ? 0.0f : __int_as_float(b.y);
                o.z = (b.z < 0) ? 0.0f : __int_as_float(b.z);
                o.w = (b.w < 0) ? 0.0f : __int_as_float(b.w);
                ((v4f*)gp)[j] = o;
            }
        }

        // re-init table for the next phase; stores stay in flight (no vmcnt)
        if (p < NPH - 1) {
            LBAR();   // stream's ds_reads complete before overwrite
            const v4i m1 = (v4i)(-1);
            #pragma unroll
            for (int j0 = 0; j0 < 4096; j0 += 1024) {
                const int j = j0 + t;
                if (j < (PCHUNK >> 2)) ((v4i*)chunk)[j] = m1;
            }
            LBAR();   // init visible before next phase's atomics
        }
    }
}

extern "C" void kernel_launch(void* const* d_in, const int* in_sizes, int n_in,
                              void* d_out, int out_size, void* d_ws, size_t ws_size,
                              hipStream_t stream) {
    const float* w_es = (const float*)d_in[0];
    const int*   x    = (const int*)d_in[1];

    float* out  = (float*)d_out;
    float* w_a  = out;                          // [256, 128000]
    float* w    = out + (size_t)BATCH * VOCAB;  // [256, 2048]

    softmax_scatter_phased<<<2 * BATCH, 1024, 0, stream>>>(w_es, x, w_a, w);
}